// Round 1
// baseline (137.813 us; speedup 1.0000x reference)
//
#include <hip/hip_runtime.h>

// LearnedTaskSpecificLinear: out[n,o] = sum_i x[n,i] * W[task_ids[n], i, o]
// x: [2048,512] f32, task_ids: [2048] i32, W: [64,512,512] f32, out: [2048,512] f32
//
// Round 6: depth-2 column-chunk pipeline per block.
//   grid (16 pair-chunks of 2x16 cols, 64 tasks) x 256 thr (4 waves).
//   LDS: Wt[2][16x512] f16 (32 KB) + per-wave row lists (1 KB) -> 4 blocks/CU;
//   __launch_bounds__(256,4) pins VGPR<=128 so occupancy is VGPR-guaranteed.
//   Schedule per block:
//     tids(vec) -> issue W-chunk0 -> ballot scan (PER-WAVE private lists, no
//     cross-wave compaction) -> x gather + f32->f16 A-frag preconvert (paf[16],
//     reused by BOTH chunks; clamped dup-address gather so idle lanes add no
//     traffic) -> W0 cvt + swizzled LDS write -> issue W-chunk1 ->
//     [lgkmcnt(0); raw s_barrier]  (W1 loads STAY IN FLIGHT across barrier)
//     -> chunk0 MFMA+store (hides W1 HBM latency) -> W1 cvt+write ->
//     [lgkmcnt(0); raw s_barrier] -> chunk1 MFMA+store -> rare >16-row loop.
//   No vmcnt(0) drain at any barrier (raw s_barrier, writer-side lgkm drain
//   only). W read from HBM exactly once grid-wide; x read once per block.

#define NDIM 512
#define KDIM 512
#define CCH  16          // cols per chunk
#define NCH  2           // chunks per block (pipeline depth)

typedef _Float16 f16x8 __attribute__((ext_vector_type(8)));
typedef float    f32x4 __attribute__((ext_vector_type(4)));
typedef int      i32x4 __attribute__((ext_vector_type(4)));

__global__ __launch_bounds__(256, 4) void k_fused2(
    const float* __restrict__ x,
    const int*   __restrict__ tids,
    const float* __restrict__ W,
    float*       __restrict__ out,
    int n_rows)
{
    const int tid  = threadIdx.x;
    const int lane = tid & 63;
    const int wv   = tid >> 6;
    const int c0   = blockIdx.x * (CCH * NCH);
    const int task = blockIdx.y;

    __shared__ __align__(16) _Float16 Wt[NCH][CCH * KDIM];   // 2 x 16 KB, [c][k] swizzled
    __shared__ unsigned short rlw[4 * 128];                  // per-wave private row lists

    // ---- tids: 8 consecutive rows per lane, vectorized (order in list is free)
    const int rbase = wv * 512 + lane * 8;
    int tval[8];
    if (rbase + 7 < n_rows) {
        const i32x4 a = *(const i32x4*)(tids + rbase);
        const i32x4 b = *(const i32x4*)(tids + rbase + 4);
        tval[0] = a[0]; tval[1] = a[1]; tval[2] = a[2]; tval[3] = a[3];
        tval[4] = b[0]; tval[5] = b[1]; tval[6] = b[2]; tval[7] = b[3];
    } else {
        #pragma unroll
        for (int j = 0; j < 8; ++j)
            tval[j] = (rbase + j < n_rows) ? tids[rbase + j] : -1;
    }

    // ---- issue W chunk-0 loads (8 x float4 per thread; latency hidden by scan)
    const int sc4   = (tid & 3) * 4;     // col group within the 16-col chunk
    const int obase = tid >> 2;          // k-octet 0..63
    const float* Wg = W + (size_t)task * KDIM * NDIM + c0;
    float4 wr[8];
    #pragma unroll
    for (int j = 0; j < 8; ++j)
        wr[j] = *(const float4*)(Wg + (size_t)(obase * 8 + j) * NDIM + sc4);

    // ---- ballot scan of this wave's quarter -> PRIVATE list (no compaction)
    int cloc = 0;
    #pragma unroll
    for (int j = 0; j < 8; ++j) {
        const bool m = (tval[j] == task);
        const unsigned long long bal = __ballot(m);
        const int rank = __popcll(bal & ((1ull << lane) - 1ull));
        if (m) rlw[wv * 128 + cloc + rank] = (unsigned short)(rbase + j);
        cloc += __popcll(bal);
    }

    const int ml = lane & 15;
    const int q  = lane >> 4;

    f16x8 paf[16];   // preconverted A-fragments, full K=512, reused by both chunks

    // Gather the wave's 16 rows (clamped: idle lanes duplicate a valid address,
    // which coalesces to zero extra traffic) and preconvert to f16 fragments.
    auto load_paf = [&](int g0) {
        const int idx = g0 + ml;
        const int nr  = (int)rlw[wv * 128 + ((idx < cloc) ? idx : (cloc - 1))];
        const float* xr = x + (size_t)nr * KDIM;
        #pragma unroll
        for (int p = 0; p < 2; ++p) {
            f32x4 xa[16];
            #pragma unroll
            for (int ks = 0; ks < 8; ++ks) {
                xa[2 * ks]     = *(const f32x4*)(xr + p * 256 + ks * 32 + q * 8);
                xa[2 * ks + 1] = *(const f32x4*)(xr + p * 256 + ks * 32 + q * 8 + 4);
            }
            #pragma unroll
            for (int ks = 0; ks < 8; ++ks) {
                f16x8 af;
                const float* a0 = (const float*)&xa[2 * ks];
                #pragma unroll
                for (int j = 0; j < 8; ++j) af[j] = (_Float16)a0[j];
                paf[p * 8 + ks] = af;
            }
        }
    };

    auto mma_tile = [&](int t) {
        f32x4 acc = {};
        #pragma unroll
        for (int p = 0; p < 2; ++p) {
            #pragma unroll
            for (int ks = 0; ks < 8; ++ks) {
                const int po = (p * 32 + ks * 4 + q) ^ (ml & 7);
                const f16x8 bf = *(const f16x8*)&Wt[t][ml * KDIM + po * 8];
                acc = __builtin_amdgcn_mfma_f32_16x16x32_f16(paf[p * 8 + ks], bf, acc, 0, 0, 0);
            }
        }
        return acc;
    };

    auto store_tile = [&](int t, int g0, f32x4 acc) {
        const int colb = c0 + t * CCH;
        #pragma unroll
        for (int rg = 0; rg < 4; ++rg) {
            const int pos = g0 + q * 4 + rg;
            if (pos < cloc)
                out[(size_t)rlw[wv * 128 + pos] * NDIM + colb + ml] = acc[rg];
        }
    };

    // ---- x gather + A-frag preconvert (pre-barrier; overlaps W0 HBM latency)
    if (cloc > 0) load_paf(0);

    // ---- W0 f32->f16 + swizzled LDS write (po = oct ^ (c&7), same as R5)
    #pragma unroll
    for (int j2 = 0; j2 < 4; ++j2) {
        f16x8 h8;
        #pragma unroll
        for (int j = 0; j < 8; ++j)
            h8[j] = (_Float16)(((const float*)&wr[j])[j2]);
        const int c  = sc4 + j2;
        const int po = obase ^ (c & 7);
        *(f16x8*)&Wt[0][c * KDIM + po * 8] = h8;
    }

    // ---- issue W chunk-1 loads: these STAY IN FLIGHT across the barrier
    #pragma unroll
    for (int j = 0; j < 8; ++j)
        wr[j] = *(const float4*)(Wg + (size_t)(obase * 8 + j) * NDIM + (CCH + sc4));

    // Writer-side LDS drain only; raw barrier does NOT wait vmcnt -> W1 in flight.
    asm volatile("s_waitcnt lgkmcnt(0)" ::: "memory");
    __builtin_amdgcn_s_barrier();
    __builtin_amdgcn_sched_barrier(0);

    // ---- chunk 0 compute+store: hides W1's HBM latency
    if (cloc > 0) store_tile(0, 0, mma_tile(0));

    // ---- W1 f32->f16 + swizzled LDS write (vmcnt wait lands here, long done)
    #pragma unroll
    for (int j2 = 0; j2 < 4; ++j2) {
        f16x8 h8;
        #pragma unroll
        for (int j = 0; j < 8; ++j)
            h8[j] = (_Float16)(((const float*)&wr[j])[j2]);
        const int c  = sc4 + j2;
        const int po = obase ^ (c & 7);
        *(f16x8*)&Wt[1][c * KDIM + po * 8] = h8;
    }

    asm volatile("s_waitcnt lgkmcnt(0)" ::: "memory");
    __builtin_amdgcn_s_barrier();
    __builtin_amdgcn_sched_barrier(0);

    // ---- chunk 1 compute+store (A-frags reused: no x re-read, no re-convert)
    if (cloc > 0) store_tile(1, 0, mma_tile(1));

    // ---- rare: waves with >16 rows in their quarter (both Wt stay resident)
    for (int g0 = 16; g0 < cloc; g0 += 16) {
        load_paf(g0);
        store_tile(0, g0, mma_tile(0));
        store_tile(1, g0, mma_tile(1));
    }
}

extern "C" void kernel_launch(void* const* d_in, const int* in_sizes, int n_in,
                              void* d_out, int out_size, void* d_ws, size_t ws_size,
                              hipStream_t stream) {
    const float* x    = (const float*)d_in[0];
    const int*   tids = (const int*)d_in[1];
    const float* W    = (const float*)d_in[2];
    float*       out  = (float*)d_out;
    const int n_rows  = in_sizes[1];   // 2048

    k_fused2<<<dim3(NDIM / (CCH * NCH), 64), dim3(256), 0, stream>>>(x, tids, W, out, n_rows);
}

// Round 2
// 107.254 us; speedup vs baseline: 1.2849x; 1.2849x over previous
//
#include <hip/hip_runtime.h>

// LearnedTaskSpecificLinear: out[n,o] = sum_i x[n,i] * W[task_ids[n], i, o]
// x: [2048,512] f32, task_ids: [2048] i32, W: [64,512,512] f32, out: [2048,512] f32
//
// Round 7: K-half depth-2 pipeline, register-budgeted (fixes R6 spill disaster).
//   grid 1024 blocks (decoded so a task's 16 col-chunks share one XCD) x 256 thr.
//   Per block: 32 cols, K split in two 256-halves, LDS Wt2[2][32x256] f16 (32 KB,
//   k-octet XOR swizzle po = oct ^ (c&7), same verified scheme as R5).
//   Schedule: tids(vec) -> issue W-h0 -> ballot scan (PER-WAVE private lists)
//     -> x-h0 load+cvt (pafA, 8-load chunks; overlaps W-h0 HBM latency)
//     -> W-h0 cvt+LDS -> issue W-h1 -> [lgkmcnt(0); s_barrier] (W-h1 IN FLIGHT)
//     -> MFMA h0 (hides W-h1 latency) -> x-h1 load+cvt (pafB) -> W-h1 cvt+LDS
//     -> [lgkmcnt(0); s_barrier] -> MFMA h1 -> store.
//   Register discipline (R6 lesson): nothing >32 VGPRs lives across a barrier.
//   Live sets: wr[8]=32, pafA/pafB=32 each (f16x8[8]), xa chunk=32, acc=8.
//   Peak ~115 < 128 cap at 4 blocks/CU. No vmcnt(0) drain at any barrier.

#define NDIM 512
#define KDIM 512
#define NCOL 32
#define KH   256

typedef _Float16 f16x8 __attribute__((ext_vector_type(8)));
typedef float    f32x4 __attribute__((ext_vector_type(4)));
typedef int      i32x4 __attribute__((ext_vector_type(4)));

__global__ __launch_bounds__(256, 4) void k_fused3(
    const float* __restrict__ x,
    const int*   __restrict__ tids,
    const float* __restrict__ W,
    float*       __restrict__ out,
    int n_rows)
{
    const int tid  = threadIdx.x;
    const int lane = tid & 63;
    const int wv   = tid >> 6;

    // XCD-clustering decode: id%8 is constant for all 16 chunks of a task,
    // so (assuming round-robin block->XCD) a task's x rows live in ONE L2.
    const int id    = blockIdx.x;
    const int task  = (id & 7) | ((id >> 7) << 3);   // bits [0:2]+[7:9]
    const int c0    = ((id >> 3) & 15) * NCOL;       // bits [3:6]

    __shared__ __align__(16) _Float16 Wt2[2][NCOL * KH];   // 2 x 16 KB, swizzled
    __shared__ unsigned short rlw[4 * 128];                // per-wave private lists

    // ---- tids: 8 consecutive rows per lane, vectorized
    const int rbase = wv * 512 + lane * 8;
    int tval[8];
    if (rbase + 7 < n_rows) {
        const i32x4 a = *(const i32x4*)(tids + rbase);
        const i32x4 b = *(const i32x4*)(tids + rbase + 4);
        tval[0] = a[0]; tval[1] = a[1]; tval[2] = a[2]; tval[3] = a[3];
        tval[4] = b[0]; tval[5] = b[1]; tval[6] = b[2]; tval[7] = b[3];
    } else {
        #pragma unroll
        for (int j = 0; j < 8; ++j)
            tval[j] = (rbase + j < n_rows) ? tids[rbase + j] : -1;
    }

    // ---- issue W half-0 (8 x float4/thread = 32 KB f32 for 32 cols x 256 k)
    const int sc4 = (tid & 7) * 4;      // col group (8 groups x 4 cols)
    const int ob  = tid >> 3;           // k-octet 0..31 within the half
    const float* Wg = W + (size_t)task * KDIM * NDIM + c0;
    float4 wr[8];
    #pragma unroll
    for (int j = 0; j < 8; ++j)
        wr[j] = *(const float4*)(Wg + (size_t)(ob * 8 + j) * NDIM + sc4);

    // ---- ballot scan -> per-wave private row list (no cross-wave compaction)
    int cloc = 0;
    #pragma unroll
    for (int j = 0; j < 8; ++j) {
        const bool m = (tval[j] == task);
        const unsigned long long bal = __ballot(m);
        const int rank = __popcll(bal & ((1ull << lane) - 1ull));
        if (m) rlw[wv * 128 + cloc + rank] = (unsigned short)(rbase + j);
        cloc += __popcll(bal);
    }

    const int ml = lane & 15;
    const int q  = lane >> 4;

    // x half -> 8 f16 A-fragments (32 VGPRs out). Loads in 8-float4 chunks so
    // transient f32 staging is only 32 VGPRs.
    auto load_half = [&](const float* xr, int t, f16x8* paf) {
        #pragma unroll
        for (int h = 0; h < 2; ++h) {
            f32x4 xa[8];
            #pragma unroll
            for (int k2 = 0; k2 < 4; ++k2) {
                const int ks = h * 4 + k2;
                xa[2 * k2]     = *(const f32x4*)(xr + t * KH + ks * 32 + q * 8);
                xa[2 * k2 + 1] = *(const f32x4*)(xr + t * KH + ks * 32 + q * 8 + 4);
            }
            #pragma unroll
            for (int k2 = 0; k2 < 4; ++k2) {
                f16x8 af;
                const float* a0 = (const float*)&xa[2 * k2];
                #pragma unroll
                for (int j = 0; j < 8; ++j) af[j] = (_Float16)a0[j];
                paf[h * 4 + k2] = af;
            }
        }
    };

    // W half: f32->f16 + swizzled LDS write (4 x b128/thread)
    auto stage_half = [&](int t) {
        #pragma unroll
        for (int j2 = 0; j2 < 4; ++j2) {
            f16x8 h8;
            #pragma unroll
            for (int j = 0; j < 8; ++j)
                h8[j] = (_Float16)(((const float*)&wr[j])[j2]);
            const int c  = sc4 + j2;
            const int po = ob ^ (c & 7);
            *(f16x8*)&Wt2[t][c * KH + po * 8] = h8;
        }
    };

    auto mma_half = [&](int t, const f16x8* paf, f32x4* acc) {
        #pragma unroll
        for (int ks = 0; ks < 8; ++ks) {
            #pragma unroll
            for (int ct = 0; ct < 2; ++ct) {
                const int cB = ct * 16 + ml;
                const int po = (ks * 4 + q) ^ (cB & 7);
                const f16x8 bf = *(const f16x8*)&Wt2[t][cB * KH + po * 8];
                acc[ct] = __builtin_amdgcn_mfma_f32_16x16x32_f16(paf[ks], bf, acc[ct], 0, 0, 0);
            }
        }
    };

    auto store_rows = [&](int g0, const f32x4* acc) {
        #pragma unroll
        for (int rg = 0; rg < 4; ++rg) {
            const int pos = g0 + q * 4 + rg;
            if (pos < cloc) {
                float* op = out + (size_t)rlw[wv * 128 + pos] * NDIM + c0 + ml;
                op[0]  = acc[0][rg];
                op[16] = acc[1][rg];
            }
        }
    };

    // ---- x half-0 gather (pre-barrier: overlaps W half-0 HBM latency).
    // Idle lanes clamp to a valid duplicate address -> coalesces, no extra traffic.
    const float* xr = x;
    f16x8 pafA[8];
    if (cloc > 0) {
        const int idx = (ml < cloc) ? ml : (cloc - 1);
        xr = x + (size_t)rlw[wv * 128 + idx] * KDIM;
        load_half(xr, 0, pafA);
    }

    // ---- W half-0 to LDS, then issue W half-1 (stays in flight across barrier)
    stage_half(0);
    #pragma unroll
    for (int j = 0; j < 8; ++j)
        wr[j] = *(const float4*)(Wg + (size_t)(KH + ob * 8 + j) * NDIM + sc4);

    asm volatile("s_waitcnt lgkmcnt(0)" ::: "memory");
    __builtin_amdgcn_s_barrier();
    __builtin_amdgcn_sched_barrier(0);

    // ---- half-0 MFMA (hides W half-1 HBM latency)
    f32x4 acc[2] = {};
    if (cloc > 0) mma_half(0, pafA, acc);

    // ---- x half-1 gather + convert (queued behind W-h1; needed only after barrier)
    f16x8 pafB[8];
    if (cloc > 0) load_half(xr, 1, pafB);

    // ---- W half-1 to LDS (compiler's vmcnt wait lands here, long since covered)
    stage_half(1);

    asm volatile("s_waitcnt lgkmcnt(0)" ::: "memory");
    __builtin_amdgcn_s_barrier();
    __builtin_amdgcn_sched_barrier(0);

    // ---- half-1 MFMA + store
    if (cloc > 0) {
        mma_half(1, pafB, acc);
        store_rows(0, acc);
    }

    // ---- rare: wave quarter with >16 matching rows (P ~ 0.3%); Wt2 resident
    for (int g0 = 16; g0 < cloc; g0 += 16) {
        const int idx = g0 + ml;
        const float* xr2 = x + (size_t)rlw[wv * 128 + ((idx < cloc) ? idx : (cloc - 1))] * KDIM;
        f16x8 pf[8];
        f32x4 a2[2] = {};
        load_half(xr2, 0, pf);
        mma_half(0, pf, a2);
        load_half(xr2, 1, pf);
        mma_half(1, pf, a2);
        store_rows(g0, a2);
    }
}

extern "C" void kernel_launch(void* const* d_in, const int* in_sizes, int n_in,
                              void* d_out, int out_size, void* d_ws, size_t ws_size,
                              hipStream_t stream) {
    const float* x    = (const float*)d_in[0];
    const int*   tids = (const int*)d_in[1];
    const float* W    = (const float*)d_in[2];
    float*       out  = (float*)d_out;
    const int n_rows  = in_sizes[1];   // 2048

    k_fused3<<<dim3(1024), dim3(256), 0, stream>>>(x, tids, W, out, n_rows);
}

// Round 4
// 105.277 us; speedup vs baseline: 1.3090x; 1.0188x over previous
//
#include <hip/hip_runtime.h>

// LearnedTaskSpecificLinear: out[n,o] = sum_i x[n,i] * W[task_ids[n], i, o]
// x: [2048,512] f32, task_ids: [2048] i32, W: [64,512,512] f32, out: [2048,512] f32
//
// Round 8b: re-run of Round 8 (previous bench died to an infra/container
// failure, not a kernel verdict; barrier/LDS audit found no hang risk).
//
// Continuous-stream 2-unit pipeline (fixes R7's one-generation burst).
//   grid 512 blocks x 256 thr, 2 blocks/CU (launch_bounds(256,2): VGPR cap 256,
//   no R6-style spills). Each block processes 2 units (task, 32-col chunk):
//   unit u0 = bid, u1 = bid + 512. Decode keeps a task's 16 chunks on one XCD
//   (bits [0:2]+[7:9] -> task), so x rows are L2-resident after first touch.
//   Per unit: K split in two 256-halves, LDS Wt[2][32x256] f16 (32 KB total,
//   k-octet XOR swizzle po = oct ^ (c&7), verified R5/R7 scheme).
//   Streaming schedule (the point of this round): W(u+1,h0) is issued BEFORE
//   unit u's second barrier, so the HBM queue never drains at unit boundaries;
//   4 load stages per block instead of R7's 2. Raw s_barrier + lgkmcnt(0) only
//   (no vmcnt drain at barriers). Register discipline: single wr[8] staging
//   buffer (32 VGPR), pafA/pafB 32 each, nothing bigger lives across a barrier.

#define NDIM 512
#define KDIM 512
#define NCOL 32
#define KH   256
#define GRID 512
#define NUNIT 2

typedef _Float16 f16x8 __attribute__((ext_vector_type(8)));
typedef float    f32x4 __attribute__((ext_vector_type(4)));
typedef int      i32x4 __attribute__((ext_vector_type(4)));

__global__ __launch_bounds__(256, 2) void k_fused4(
    const float* __restrict__ x,
    const int*   __restrict__ tids,
    const float* __restrict__ W,
    float*       __restrict__ out,
    int n_rows)
{
    const int tid  = threadIdx.x;
    const int lane = tid & 63;
    const int wv   = tid >> 6;
    const int ml   = lane & 15;
    const int q    = lane >> 4;
    const int sc4  = (tid & 7) * 4;     // W col group (8 groups x 4 cols)
    const int ob   = tid >> 3;          // W k-octet 0..31 within a half

    __shared__ __align__(16) _Float16 Wt[2][NCOL * KH];   // 2 x 16 KB, swizzled
    __shared__ unsigned short rlw[4 * 128];               // per-wave private lists

    // ---- tids: 8 consecutive rows per lane, vectorized; kept in regs for both units
    const int rbase = wv * 512 + lane * 8;
    int tval[8];
    if (rbase + 7 < n_rows) {
        const i32x4 a = *(const i32x4*)(tids + rbase);
        const i32x4 b = *(const i32x4*)(tids + rbase + 4);
        tval[0] = a[0]; tval[1] = a[1]; tval[2] = a[2]; tval[3] = a[3];
        tval[4] = b[0]; tval[5] = b[1]; tval[6] = b[2]; tval[7] = b[3];
    } else {
        #pragma unroll
        for (int j = 0; j < 8; ++j)
            tval[j] = (rbase + j < n_rows) ? tids[rbase + j] : -1;
    }

    // ---- mutable per-unit state (declared before lambdas so they capture it)
    int   cloc = 0;
    int   c0   = 0;
    const float* xr = x;
    float4 wr[8];

    auto issueW = [&](const float* Wg, int h) {
        #pragma unroll
        for (int j = 0; j < 8; ++j)
            wr[j] = *(const float4*)(Wg + (size_t)(h * KH + ob * 8 + j) * NDIM + sc4);
    };

    auto stageW = [&](int t) {      // f32->f16 + swizzled LDS write, 4 x b128
        #pragma unroll
        for (int j2 = 0; j2 < 4; ++j2) {
            f16x8 h8;
            #pragma unroll
            for (int j = 0; j < 8; ++j)
                h8[j] = (_Float16)(((const float*)&wr[j])[j2]);
            const int c  = sc4 + j2;
            const int po = ob ^ (c & 7);
            *(f16x8*)&Wt[t][c * KH + po * 8] = h8;
        }
    };

    auto load_half = [&](const float* xrp, int t, f16x8* paf) {
        #pragma unroll
        for (int h = 0; h < 2; ++h) {
            f32x4 xa[8];
            #pragma unroll
            for (int k2 = 0; k2 < 4; ++k2) {
                const int ks = h * 4 + k2;
                xa[2 * k2]     = *(const f32x4*)(xrp + t * KH + ks * 32 + q * 8);
                xa[2 * k2 + 1] = *(const f32x4*)(xrp + t * KH + ks * 32 + q * 8 + 4);
            }
            #pragma unroll
            for (int k2 = 0; k2 < 4; ++k2) {
                f16x8 af;
                const float* a0 = (const float*)&xa[2 * k2];
                #pragma unroll
                for (int j = 0; j < 8; ++j) af[j] = (_Float16)a0[j];
                paf[h * 4 + k2] = af;
            }
        }
    };

    auto mma_half = [&](int t, const f16x8* paf, f32x4* acc) {
        #pragma unroll
        for (int ks = 0; ks < 8; ++ks) {
            #pragma unroll
            for (int ct = 0; ct < 2; ++ct) {
                const int cB = ct * 16 + ml;
                const int po = (ks * 4 + q) ^ (cB & 7);
                const f16x8 bf = *(const f16x8*)&Wt[t][cB * KH + po * 8];
                acc[ct] = __builtin_amdgcn_mfma_f32_16x16x32_f16(paf[ks], bf, acc[ct], 0, 0, 0);
            }
        }
    };

    auto store_rows = [&](int g0, const f32x4* acc) {
        #pragma unroll
        for (int rg = 0; rg < 4; ++rg) {
            const int pos = g0 + q * 4 + rg;
            if (pos < cloc) {
                float* op = out + (size_t)rlw[wv * 128 + pos] * NDIM + c0 + ml;
                op[0]  = acc[0][rg];
                op[16] = acc[1][rg];
            }
        }
    };

    // ---- unit 0 decode + first W issue (before anything else waits)
    int task = (blockIdx.x & 7) | ((blockIdx.x >> 7) << 3);
    c0 = ((blockIdx.x >> 3) & 15) * NCOL;
    const float* Wg = W + (size_t)task * KDIM * NDIM + c0;
    issueW(Wg, 0);

    #pragma unroll
    for (int uu = 0; uu < NUNIT; ++uu) {
        // ---- ballot scan -> per-wave private row list (rlw region is wave-private,
        // so rewriting it each unit needs no barrier)
        cloc = 0;
        #pragma unroll
        for (int j = 0; j < 8; ++j) {
            const bool m = (tval[j] == task);
            const unsigned long long bal = __ballot(m);
            const int rank = __popcll(bal & ((1ull << lane) - 1ull));
            if (m) rlw[wv * 128 + cloc + rank] = (unsigned short)(rbase + j);
            cloc += __popcll(bal);
        }

        // ---- x half-0 gather (clamped dup addresses for idle lanes -> coalesced)
        f16x8 pafA[8], pafB[8];
        if (cloc > 0) {
            const int idx = (ml < cloc) ? ml : (cloc - 1);
            xr = x + (size_t)rlw[wv * 128 + idx] * KDIM;
            load_half(xr, 0, pafA);
        }

        // ---- W h0 -> LDS, issue W h1 (stays in flight across the barrier)
        stageW(0);
        issueW(Wg, 1);
        asm volatile("s_waitcnt lgkmcnt(0)" ::: "memory");
        __builtin_amdgcn_s_barrier();
        __builtin_amdgcn_sched_barrier(0);

        // ---- half-0 MFMA (hides W h1 latency), x h1 gather, W h1 -> LDS
        f32x4 acc[2] = {};
        if (cloc > 0) mma_half(0, pafA, acc);
        if (cloc > 0) load_half(xr, 1, pafB);
        stageW(1);

        // ---- cross-unit prefetch: issue next unit's W h0 BEFORE the barrier,
        // so the HBM queue never drains at the unit boundary (the round's point)
        int ntask = 0, nc0 = 0;
        const float* nWg = nullptr;
        if (uu + 1 < NUNIT) {
            const int nu = blockIdx.x + (uu + 1) * GRID;
            ntask = (nu & 7) | ((nu >> 7) << 3);
            nc0   = ((nu >> 3) & 15) * NCOL;
            nWg   = W + (size_t)ntask * KDIM * NDIM + nc0;
            issueW(nWg, 0);
        }

        asm volatile("s_waitcnt lgkmcnt(0)" ::: "memory");
        __builtin_amdgcn_s_barrier();
        __builtin_amdgcn_sched_barrier(0);

        // ---- half-1 MFMA + store
        if (cloc > 0) {
            mma_half(1, pafB, acc);
            store_rows(0, acc);
        }

        // ---- rare: wave quarter with >16 matching rows; both Wt halves resident
        for (int g0 = 16; g0 < cloc; g0 += 16) {
            const int idx = g0 + ml;
            const float* xr2 = x + (size_t)rlw[wv * 128 + ((idx < cloc) ? idx : (cloc - 1))] * KDIM;
            f16x8 pf[8];
            f32x4 a2[2] = {};
            load_half(xr2, 0, pf);
            mma_half(0, pf, a2);
            load_half(xr2, 1, pf);
            mma_half(1, pf, a2);
            store_rows(g0, a2);
        }

        // ---- hand off to next unit; barrier protects Wt overwrite vs any wave
        // still reading (extras loop). Next unit's W h0 remains in flight.
        if (uu + 1 < NUNIT) {
            asm volatile("s_waitcnt lgkmcnt(0)" ::: "memory");
            __builtin_amdgcn_s_barrier();
            __builtin_amdgcn_sched_barrier(0);
            task = ntask; c0 = nc0; Wg = nWg;
        }
    }
}

extern "C" void kernel_launch(void* const* d_in, const int* in_sizes, int n_in,
                              void* d_out, int out_size, void* d_ws, size_t ws_size,
                              hipStream_t stream) {
    const float* x    = (const float*)d_in[0];
    const int*   tids = (const int*)d_in[1];
    const float* W    = (const float*)d_in[2];
    float*       out  = (float*)d_out;
    const int n_rows  = in_sizes[1];   // 2048

    k_fused4<<<dim3(GRID), dim3(256), 0, stream>>>(x, tids, W, out, n_rows);
}